// Round 1
// 849.223 us; speedup vs baseline: 1.0149x; 1.0149x over previous
//
#include <hip/hip_runtime.h>

typedef _Float16 f16x8 __attribute__((ext_vector_type(8)));
typedef _Float16 f16x4 __attribute__((ext_vector_type(4)));
typedef float f32x4 __attribute__((ext_vector_type(4)));

#define BN   65536   // B*N = 16*4096
#define MSZ  4096
#define TOPK 8

#define MFMA(a, b, c) __builtin_amdgcn_mfma_f32_16x16x32_f16(a, b, c, 0, 0, 0)

// ---------------------------------------------------------------------------
// Prep: fp32 -> fp16 flat convert (keys)
// ---------------------------------------------------------------------------
__global__ void cvt_f16(const float* __restrict__ src, _Float16* __restrict__ dst,
                        int n) {
    int i = blockIdx.x * 256 + threadIdx.x;
    if (i < n) dst[i] = (_Float16)src[i];
}

// ---------------------------------------------------------------------------
// Prep: dst[n*K + k] = (f16)src[k*N + n]
// ---------------------------------------------------------------------------
__global__ void cvt_transpose(const float* __restrict__ src, _Float16* __restrict__ dst,
                              int K, int N) {
    int i = blockIdx.x * 256 + threadIdx.x;
    if (i < K * N) {
        int k = i / N, n = i - k * N;
        dst[n * K + k] = (_Float16)src[i];
    }
}

// ---------------------------------------------------------------------------
// Packed selection key: [31:12] = ordered-uint fp32 score (truncated),
// [11:0] = ~idx (12 bits) -> bigger key = higher score, ties: lower idx wins.
// ---------------------------------------------------------------------------
__device__ __forceinline__ unsigned pack_key(float s, unsigned inv12) {
    unsigned u = __float_as_uint(s);
    unsigned m = (unsigned)(((int)u) >> 31) | 0x80000000u;
    unsigned k = u ^ m;                       // ordered mapping
    return (k & 0xFFFFF000u) | inv12;
}

// Branchless insert into sorted-descending list t[0..N-1] (u32, larger=better)
template <int N>
__device__ __forceinline__ void ins(unsigned* t, unsigned key) {
#pragma unroll
    for (int p = N - 1; p > 0; --p) {
        unsigned keep = (t[p] > key) ? t[p] : key;
        t[p] = (key >= t[p - 1]) ? t[p - 1] : keep;
    }
    t[0] = (t[0] > key) ? t[0] : key;
}

// ---------------------------------------------------------------------------
// Fully fused: proj -> sim -> top8 -> softmax -> gather -> MLP1 -> MLP2.
// 32 rows / block, 256 threads. Sim phase is BARRIER-FREE: each thread keeps
// top-6 packed keys per (row, col-slice) stream in registers; exact top-8 per
// row is rebuilt by an IN-REGISTER shuffle butterfly (within-quad l16 xor
// 1/2/4/8), then one tiny 4-way LDS merge. All list indices are compile-time
// (value-select via cndmask, never runtime array index -> no scratch).
// LDS: 39424 B -> 4 blocks/CU (was 53760 B -> 3 blocks/CU).
// ---------------------------------------------------------------------------
__global__ __launch_bounds__(256, 4) void fused_all(
        const float*    __restrict__ query,   // BN x 256 fp32
        const _Float16* __restrict__ keysH,   // 4096 x 256 f16 (ws)
        const float*    __restrict__ vals,    // 4096 x 256 fp32
        const _Float16* __restrict__ WqT,     // 256 x 256 f16 (ws, transposed)
        const float*    __restrict__ bq,
        const _Float16* __restrict__ W1T,     // 256 x 512 f16 (ws, transposed)
        const float*    __restrict__ b1,
        const _Float16* __restrict__ W2T,     // 256 x 256 f16 (ws, transposed)
        const float*    __restrict__ b2,
        float* __restrict__ out)              // BN x 256 fp32
{
    constexpr int ROWS = 32;
    __shared__ __attribute__((aligned(16))) _Float16 AA[ROWS][520];  // 33280 B
    __shared__ unsigned Wbuf[4][ROWS][TOPK];                         //  4096 B
    __shared__ float Fs[ROWS][TOPK];                                 //  1024 B
    __shared__ int   Fi[ROWS][TOPK];                                 //  1024 B

    const int tid  = threadIdx.x;
    const int lane = tid & 63, quad = lane >> 4, l16 = lane & 15, wave = tid >> 6;
    const size_t row0 = (size_t)blockIdx.x * ROWS;

    // ---- P0: stage 32 query rows (fp32 -> f16) into AA[:, 0:256) ----
    for (int v = tid; v < 2048; v += 256) {
        int r = v >> 6, c = (v & 63) * 4;
        float4 f = *(const float4*)(query + (row0 + r) * 256 + c);
        f16x4 h = {(_Float16)f.x, (_Float16)f.y, (_Float16)f.z, (_Float16)f.w};
        *(f16x4*)&AA[r][c] = h;
    }
    __syncthreads();

    // ---- P1: qproj = query @ Wq + bq -> AA[:, 256:512) ----
    {
        f32x4 acc[2][4];
#pragma unroll
        for (int rt = 0; rt < 2; ++rt)
#pragma unroll
            for (int nt = 0; nt < 4; ++nt)
                acc[rt][nt] = (f32x4){0.f, 0.f, 0.f, 0.f};
#pragma unroll
        for (int kf = 0; kf < 8; ++kf) {
            f16x8 a0 = *(const f16x8*)&AA[l16][kf * 32 + quad * 8];
            f16x8 a1 = *(const f16x8*)&AA[l16 + 16][kf * 32 + quad * 8];
#pragma unroll
            for (int nt = 0; nt < 4; ++nt) {
                int n0 = wave * 16 + nt * 64;
                f16x8 b = *(const f16x8*)(WqT + (size_t)(n0 + l16) * 256 + kf * 32 + quad * 8);
                acc[0][nt] = MFMA(a0, b, acc[0][nt]);
                acc[1][nt] = MFMA(a1, b, acc[1][nt]);
            }
        }
#pragma unroll
        for (int nt = 0; nt < 4; ++nt) {
            int col = wave * 16 + nt * 64 + l16;
            float bv = bq[col];
#pragma unroll
            for (int rt = 0; rt < 2; ++rt)
#pragma unroll
                for (int r = 0; r < 4; ++r)
                    AA[rt * 16 + quad * 4 + r][256 + col] = (_Float16)(acc[rt][nt][r] + bv);
        }
    }
    __syncthreads();

    // ---- P2: sim = qproj @ keys^T, barrier-free register top-6 per stream ----
    f16x8 af0[8], af1[8];
#pragma unroll
    for (int nk = 0; nk < 8; ++nk) {
        af0[nk] = *(const f16x8*)&AA[l16][256 + nk * 32 + quad * 8];
        af1[nk] = *(const f16x8*)&AA[l16 + 16][256 + nk * 32 + quad * 8];
    }

    unsigned tk[8][6];   // 8 streams: rows quad*4+r (0..3) and 16+quad*4+r (4..7)
#pragma unroll
    for (int s = 0; s < 8; ++s)
#pragma unroll
        for (int e = 0; e < 6; ++e) tk[s][e] = 0u;

    for (int m0 = 0; m0 < MSZ; m0 += 64) {
        f32x4 acc0 = {0.f, 0.f, 0.f, 0.f};
        f32x4 acc1 = {0.f, 0.f, 0.f, 0.f};
        const _Float16* bp = keysH + (size_t)(m0 + wave * 16 + l16) * 256 + quad * 8;
#pragma unroll
        for (int nk = 0; nk < 8; ++nk) {
            f16x8 b = *(const f16x8*)(bp + nk * 32);
            acc0 = MFMA(af0[nk], b, acc0);
            acc1 = MFMA(af1[nk], b, acc1);
        }
        unsigned inv12 = (~(unsigned)(m0 + wave * 16 + l16)) & 0xFFFu;
#pragma unroll
        for (int r = 0; r < 4; ++r) ins<6>(tk[r],     pack_key(acc0[r], inv12));
#pragma unroll
        for (int r = 0; r < 4; ++r) ins<6>(tk[4 + r], pack_key(acc1[r], inv12));
    }

    // ---- in-register butterfly merge over the 16 l16 col-slices (in-quad).
    // Stage 1 (128-col window, depth 6): split 8 streams -> 4 per lane.
    unsigned m4[4][6];
    {
        const unsigned kh = l16 & 1;          // 1: keep streams 4-7
#pragma unroll
        for (int j = 0; j < 4; ++j)
#pragma unroll
            for (int e = 0; e < 6; ++e)
                m4[j][e] = kh ? tk[4 + j][e] : tk[j][e];
#pragma unroll
        for (int j = 0; j < 4; ++j)
#pragma unroll
            for (int e = 0; e < 6; ++e) {
                unsigned snd = kh ? tk[j][e] : tk[4 + j][e];
                unsigned rcv = __shfl_xor(snd, 1);
                ins<6>(m4[j], rcv);
            }
    }
    // Stage 2 (256-col window): 4 -> 2 streams, grow depth to 8 (exact beyond).
    unsigned m2[2][8];
    {
        const unsigned k2 = (l16 >> 1) & 1;   // 1: keep m4[2..3]
#pragma unroll
        for (int j = 0; j < 2; ++j) {
#pragma unroll
            for (int e = 0; e < 6; ++e)
                m2[j][e] = k2 ? m4[2 + j][e] : m4[j][e];
            m2[j][6] = 0u; m2[j][7] = 0u;
        }
#pragma unroll
        for (int j = 0; j < 2; ++j)
#pragma unroll
            for (int e = 0; e < 6; ++e) {
                unsigned snd = k2 ? m4[j][e] : m4[2 + j][e];
                unsigned rcv = __shfl_xor(snd, 2);
                ins<8>(m2[j], rcv);
            }
    }
    // Stage 3 (512-col window): 2 -> 1 stream, depth 8.
    unsigned m1[8];
    {
        const unsigned k3 = (l16 >> 2) & 1;   // 1: keep m2[1]
#pragma unroll
        for (int e = 0; e < 8; ++e) m1[e] = k3 ? m2[1][e] : m2[0][e];
#pragma unroll
        for (int e = 0; e < 8; ++e) {
            unsigned snd = k3 ? m2[0][e] : m2[1][e];
            unsigned rcv = __shfl_xor(snd, 4);
            ins<8>(m1, rcv);
        }
    }
    // Stage 4 (1024-col window = whole wave slice): snapshot first, then merge
    // (sends must not observe partially-updated m1).
    {
        unsigned rcv4[8];
#pragma unroll
        for (int e = 0; e < 8; ++e) rcv4[e] = __shfl_xor(m1[e], 8);
#pragma unroll
        for (int e = 0; e < 8; ++e) ins<8>(m1, rcv4[e]);
    }
    // Dump per-wave top-8: lane l16<8 owns stream s = (bit0<<2)|(bit1<<1)|bit2.
    if (l16 < 8) {
        const int s = ((l16 & 1) << 2) | (l16 & 2) | ((l16 >> 2) & 1);
        const int row = ((s & 4) ? 16 : 0) + quad * 4 + (s & 3);
#pragma unroll
        for (int e = 0; e < 8; ++e) Wbuf[wave][row][e] = m1[e];
    }
    __syncthreads();

    // ---- final 4-way merge (exact: depth-8 lists) + index extraction ----
    if (tid < 32) {
        unsigned f[8];
#pragma unroll
        for (int e = 0; e < 8; ++e) f[e] = Wbuf[0][tid][e];
        for (int w = 1; w < 4; ++w)
#pragma unroll
            for (int e = 0; e < 8; ++e) ins<8>(f, Wbuf[w][tid][e]);
#pragma unroll
        for (int k = 0; k < TOPK; ++k)
            Fi[tid][k] = 4095 - (int)(f[k] & 0xFFFu);
    }
    __syncthreads();

    // ---- recompute accurate fp32 scores + softmax weights ----
    {
        int r = tid >> 3, j = tid & 7;
        int idx = Fi[r][j] & (MSZ - 1);
        const f16x8* kp = (const f16x8*)(keysH + (size_t)idx * 256);
        float s = 0.f;
#pragma unroll
        for (int v = 0; v < 32; ++v) {
            f16x8 kv = kp[v];
            f16x8 qv = *(const f16x8*)&AA[r][256 + v * 8];
#pragma unroll
            for (int e = 0; e < 8; ++e) s += (float)qv[e] * (float)kv[e];
        }
        float mx = s;
#pragma unroll
        for (int off = 1; off < 8; off <<= 1) mx = fmaxf(mx, __shfl_xor(mx, off));
        float w = __expf(s - mx);
        float z = w;
#pragma unroll
        for (int off = 1; off < 8; off <<= 1) z += __shfl_xor(z, off);
        Fs[r][j] = w / z;
    }
    __syncthreads();

    // ---- P3: weighted gather of values (fp32) -> AA[:, 256:512) ----
    {
        const int r = tid >> 3, f0 = (tid & 7) * 32;
        float rv[32];
#pragma unroll
        for (int t = 0; t < 32; ++t) rv[t] = 0.f;
        for (int jj = 0; jj < TOPK; ++jj) {
            float wgt = Fs[r][jj];
            int idx = Fi[r][jj] & (MSZ - 1);
            const float4* vp = (const float4*)(vals + (size_t)idx * 256 + f0);
#pragma unroll
            for (int vv = 0; vv < 8; ++vv) {
                float4 vb = vp[vv];
                rv[vv * 4 + 0] += wgt * vb.x;
                rv[vv * 4 + 1] += wgt * vb.y;
                rv[vv * 4 + 2] += wgt * vb.z;
                rv[vv * 4 + 3] += wgt * vb.w;
            }
        }
#pragma unroll
        for (int t = 0; t < 32; ++t) AA[r][256 + f0 + t] = (_Float16)rv[t];
    }
    __syncthreads();

    // ---- P4: h = relu([query|retrieved] @ W1 + b1) -> AA[:, 0:256) ----
    {
        f32x4 acc[2][4];
#pragma unroll
        for (int rt = 0; rt < 2; ++rt)
#pragma unroll
            for (int nt = 0; nt < 4; ++nt)
                acc[rt][nt] = (f32x4){0.f, 0.f, 0.f, 0.f};
#pragma unroll
        for (int kf = 0; kf < 16; ++kf) {
            f16x8 a0 = *(const f16x8*)&AA[l16][kf * 32 + quad * 8];
            f16x8 a1 = *(const f16x8*)&AA[l16 + 16][kf * 32 + quad * 8];
#pragma unroll
            for (int nt = 0; nt < 4; ++nt) {
                int n0 = wave * 16 + nt * 64;
                f16x8 b = *(const f16x8*)(W1T + (size_t)(n0 + l16) * 512 + kf * 32 + quad * 8);
                acc[0][nt] = MFMA(a0, b, acc[0][nt]);
                acc[1][nt] = MFMA(a1, b, acc[1][nt]);
            }
        }
        __syncthreads();  // drain AA reads before overwriting cols 0:256
#pragma unroll
        for (int nt = 0; nt < 4; ++nt) {
            int col = wave * 16 + nt * 64 + l16;
            float bv = b1[col];
#pragma unroll
            for (int rt = 0; rt < 2; ++rt)
#pragma unroll
                for (int r = 0; r < 4; ++r)
                    AA[rt * 16 + quad * 4 + r][col] =
                        (_Float16)fmaxf(acc[rt][nt][r] + bv, 0.f);
        }
    }
    __syncthreads();

    // ---- P5: out = h @ W2 + b2 -> global (fp32) ----
    {
        f32x4 acc[2][4];
#pragma unroll
        for (int rt = 0; rt < 2; ++rt)
#pragma unroll
            for (int nt = 0; nt < 4; ++nt)
                acc[rt][nt] = (f32x4){0.f, 0.f, 0.f, 0.f};
#pragma unroll
        for (int kf = 0; kf < 8; ++kf) {
            f16x8 a0 = *(const f16x8*)&AA[l16][kf * 32 + quad * 8];
            f16x8 a1 = *(const f16x8*)&AA[l16 + 16][kf * 32 + quad * 8];
#pragma unroll
            for (int nt = 0; nt < 4; ++nt) {
                int n0 = wave * 16 + nt * 64;
                f16x8 b = *(const f16x8*)(W2T + (size_t)(n0 + l16) * 256 + kf * 32 + quad * 8);
                acc[0][nt] = MFMA(a0, b, acc[0][nt]);
                acc[1][nt] = MFMA(a1, b, acc[1][nt]);
            }
        }
#pragma unroll
        for (int nt = 0; nt < 4; ++nt) {
            int col = wave * 16 + nt * 64 + l16;
            float bv = b2[col];
#pragma unroll
            for (int rt = 0; rt < 2; ++rt)
#pragma unroll
                for (int r = 0; r < 4; ++r)
                    out[(row0 + rt * 16 + quad * 4 + r) * 256 + col] =
                        acc[rt][nt][r] + bv;
        }
    }
}

// ---------------------------------------------------------------------------
extern "C" void kernel_launch(void* const* d_in, const int* in_sizes, int n_in,
                              void* d_out, int out_size, void* d_ws, size_t ws_size,
                              hipStream_t stream) {
    const float* query = (const float*)d_in[0];
    const float* keys  = (const float*)d_in[1];
    const float* vals  = (const float*)d_in[2];
    const float* Wq    = (const float*)d_in[3];
    const float* bq    = (const float*)d_in[4];
    const float* W1    = (const float*)d_in[5];
    const float* b1    = (const float*)d_in[6];
    const float* W2    = (const float*)d_in[7];
    const float* b2    = (const float*)d_in[8];
    float* out = (float*)d_out;

    // ws layout (f16): keysH 2 MB @ 0 | WqT 128K | W1T 256K | W2T 128K = 2.5 MB
    char* ws = (char*)d_ws;
    _Float16* keysH = (_Float16*)(ws);
    _Float16* WqT   = (_Float16*)(ws + 2097152);
    _Float16* W1T   = (_Float16*)(ws + 2097152 + 131072);
    _Float16* W2T   = (_Float16*)(ws + 2097152 + 131072 + 262144);

    cvt_f16<<<4096, 256, 0, stream>>>(keys, keysH, MSZ * 256);
    cvt_transpose<<<256, 256, 0, stream>>>(Wq, WqT, 256, 256);
    cvt_transpose<<<512, 256, 0, stream>>>(W1, W1T, 512, 256);
    cvt_transpose<<<256, 256, 0, stream>>>(W2, W2T, 256, 256);

    fused_all<<<BN / 32, 256, 0, stream>>>(query, keysH, vals, WqT, bq,
                                           W1T, b1, W2T, b2, out);
}